// Round 1
// baseline (192.020 us; speedup 1.0000x reference)
//
#include <hip/hip_runtime.h>

// Problem constants (from reference): x[N][D], weight[CH][D], out[CH][D] fp32.
constexpr int N_ROWS = 65536;
constexpr int D      = 1024;
constexpr int CH     = 128;

// ---------------------------------------------------------------------------
// K1: partial column sums of x. Each block owns a contiguous slab of
// rows_per_chunk rows; 256 threads x float4 = exactly one 1024-col row per
// iteration -> perfectly coalesced streaming. Deterministic (fixed order).
// ---------------------------------------------------------------------------
__global__ void colsum_partial_kernel(const float* __restrict__ x,
                                      float* __restrict__ partial,
                                      int rows_per_chunk) {
    const int chunk = blockIdx.x;
    const int tid   = threadIdx.x;  // 0..255, owns 4 consecutive columns
    const float4* __restrict__ xr =
        reinterpret_cast<const float4*>(x) +
        (size_t)chunk * rows_per_chunk * (D / 4) + tid;
    float4 acc = make_float4(0.f, 0.f, 0.f, 0.f);
    for (int r = 0; r < rows_per_chunk; ++r) {
        float4 v = xr[(size_t)r * (D / 4)];
        acc.x += v.x; acc.y += v.y; acc.z += v.z; acc.w += v.w;
    }
    reinterpret_cast<float4*>(partial)[(size_t)chunk * (D / 4) + tid] = acc;
}

// ---------------------------------------------------------------------------
// K2: reduce partials -> c[1024]; column-sum weight -> t[1024].
// 4 blocks x 256 threads; coalesced reads (consecutive j within a chunk row).
// ---------------------------------------------------------------------------
__global__ void reduce_ct_kernel(const float* __restrict__ partial, int nchunk,
                                 const float* __restrict__ w,
                                 float* __restrict__ c, float* __restrict__ t) {
    const int j = blockIdx.x * blockDim.x + threadIdx.x;  // 0..1023
    float acc = 0.f;
    for (int ch = 0; ch < nchunk; ++ch) acc += partial[(size_t)ch * D + j];
    c[j] = acc;
    float tt = 0.f;
    for (int i = 0; i < CH; ++i) tt += w[(size_t)i * D + j];
    t[j] = tt;
}

// ---------------------------------------------------------------------------
// K3: one block per output row i.
//   s_i  = sum(weight[i,:])            (LDS tree reduce, deterministic)
//   det_i= sum_k exp(s_i * c[k])       (LDS tree reduce)
//   out[i,j] = exp(s_i * t[j]) / det_i (float4 store)
// ---------------------------------------------------------------------------
__global__ void out_kernel(const float* __restrict__ w,
                           const float* __restrict__ c,
                           const float* __restrict__ t,
                           float* __restrict__ out) {
    const int i   = blockIdx.x;
    const int tid = threadIdx.x;  // 0..255

    __shared__ float red[256];

    // s_i: 256 threads x float4 = 1024 elements of weight row i
    float4 wv = reinterpret_cast<const float4*>(w + (size_t)i * D)[tid];
    red[tid] = wv.x + wv.y + wv.z + wv.w;
    __syncthreads();
    for (int sft = 128; sft > 0; sft >>= 1) {
        if (tid < sft) red[tid] += red[tid + sft];
        __syncthreads();
    }
    const float s_i = red[0];
    __syncthreads();

    // det_i = sum_k exp(s_i * c[k])
    float4 cv = reinterpret_cast<const float4*>(c)[tid];
    red[tid] = expf(s_i * cv.x) + expf(s_i * cv.y) +
               expf(s_i * cv.z) + expf(s_i * cv.w);
    __syncthreads();
    for (int sft = 128; sft > 0; sft >>= 1) {
        if (tid < sft) red[tid] += red[tid + sft];
        __syncthreads();
    }
    const float inv_det = 1.0f / red[0];

    // out row
    float4 tv = reinterpret_cast<const float4*>(t)[tid];
    float4 o;
    o.x = expf(s_i * tv.x) * inv_det;
    o.y = expf(s_i * tv.y) * inv_det;
    o.z = expf(s_i * tv.z) * inv_det;
    o.w = expf(s_i * tv.w) * inv_det;
    reinterpret_cast<float4*>(out + (size_t)i * D)[tid] = o;
}

// ---------------------------------------------------------------------------
// launch
// ---------------------------------------------------------------------------
extern "C" void kernel_launch(void* const* d_in, const int* in_sizes, int n_in,
                              void* d_out, int out_size, void* d_ws, size_t ws_size,
                              hipStream_t stream) {
    const float* x = (const float*)d_in[0];   // [N_ROWS, D]
    const float* w = (const float*)d_in[1];   // [CH, D]
    float* out = (float*)d_out;               // [CH, D]

    char* ws = (char*)d_ws;
    float* c       = (float*)(ws);            // 1024 floats
    float* t       = (float*)(ws + 4096);     // 1024 floats
    float* partial = (float*)(ws + 8192);     // nchunk * 1024 floats

    // nchunk: power of two dividing N_ROWS, capped by workspace availability.
    size_t avail = (ws_size > 8192) ? (ws_size - 8192) : 0;
    int max_chunks = (int)(avail / (D * sizeof(float)));
    int nchunk = 512;  // 512 blocks -> 2 blocks/CU, 8 waves/CU on K1
    while (nchunk > 1 && nchunk > max_chunks) nchunk >>= 1;
    const int rows_per_chunk = N_ROWS / nchunk;

    colsum_partial_kernel<<<nchunk, 256, 0, stream>>>(x, partial, rows_per_chunk);
    reduce_ct_kernel<<<D / 256, 256, 0, stream>>>(partial, nchunk, w, c, t);
    out_kernel<<<CH, 256, 0, stream>>>(w, c, t, out);
}

// Round 2
// 78.479 us; speedup vs baseline: 2.4468x; 2.4468x over previous
//
#include <hip/hip_runtime.h>

// Reference: x[65536][1024] f32, weight[128][1024] f32 -> out[128][1024] f32.
// out[i,j] = exp(s_i*t_j)/det_i, s=rowsum(w), t=colsum(w), c=colsum(x),
// det_i = sum_k exp(s_i*c_k).  Bottleneck: 256 MiB read of x (colsum).
constexpr int N_ROWS = 65536;
constexpr int D      = 1024;
constexpr int CH     = 128;
constexpr int NCHUNK_DEFAULT = 1024;   // 64 rows/chunk; 4 blocks/CU, 16 waves/CU

// ---------------------------------------------------------------------------
// K1: partial column sums of x. Block = one contiguous 64-row slab.
// 256 thr x float4 covers a full 1024-col row per step; manual 4-deep unroll
// with 4 independent accumulators -> 16 KiB in flight per wave.
// ---------------------------------------------------------------------------
__global__ __launch_bounds__(256) void colsum_partial_kernel(
    const float* __restrict__ x, float* __restrict__ partial, int rows) {
    const int chunk = blockIdx.x;
    const int tid   = threadIdx.x;
    const float4* __restrict__ xr =
        reinterpret_cast<const float4*>(x) + (size_t)chunk * rows * (D / 4) + tid;

    float4 a0 = {0, 0, 0, 0}, a1 = {0, 0, 0, 0}, a2 = {0, 0, 0, 0}, a3 = {0, 0, 0, 0};
    for (int r = 0; r < rows; r += 4) {
        float4 v0 = xr[(size_t)(r + 0) * (D / 4)];
        float4 v1 = xr[(size_t)(r + 1) * (D / 4)];
        float4 v2 = xr[(size_t)(r + 2) * (D / 4)];
        float4 v3 = xr[(size_t)(r + 3) * (D / 4)];
        a0.x += v0.x; a0.y += v0.y; a0.z += v0.z; a0.w += v0.w;
        a1.x += v1.x; a1.y += v1.y; a1.z += v1.z; a1.w += v1.w;
        a2.x += v2.x; a2.y += v2.y; a2.z += v2.z; a2.w += v2.w;
        a3.x += v3.x; a3.y += v3.y; a3.z += v3.z; a3.w += v3.w;
    }
    float4 o;
    o.x = (a0.x + a1.x) + (a2.x + a3.x);
    o.y = (a0.y + a1.y) + (a2.y + a3.y);
    o.z = (a0.z + a1.z) + (a2.z + a3.z);
    o.w = (a0.w + a1.w) + (a2.w + a3.w);
    reinterpret_cast<float4*>(partial)[(size_t)chunk * (D / 4) + tid] = o;
}

// ---------------------------------------------------------------------------
// K2: blocks 0..15 reduce partial[nchunk][1024] -> c[1024];
//     blocks 16..31 column-sum weight -> t[1024].
// Block owns 64 columns; 256 thr = 4 chunk-groups x 64 cols; LDS combine.
// Fixed reduction order -> deterministic.
// ---------------------------------------------------------------------------
__global__ __launch_bounds__(256) void reduce_ct_kernel(
    const float* __restrict__ partial, int nchunk,
    const float* __restrict__ w,
    float* __restrict__ c, float* __restrict__ t) {
    const int b   = blockIdx.x;
    const int tid = threadIdx.x;
    const int col_in_blk = tid & 63;
    const int grp        = tid >> 6;  // 0..3
    __shared__ float red[4][64];

    if (b < 16) {
        const int col = b * 64 + col_in_blk;
        const int cpg = nchunk >> 2;  // chunks per group
        const float* __restrict__ p = partial + (size_t)grp * cpg * D + col;
        float acc = 0.f;
        #pragma unroll 8
        for (int ch = 0; ch < cpg; ++ch) acc += p[(size_t)ch * D];
        red[grp][col_in_blk] = acc;
        __syncthreads();
        if (grp == 0)
            c[col] = (red[0][col_in_blk] + red[1][col_in_blk]) +
                     (red[2][col_in_blk] + red[3][col_in_blk]);
    } else {
        const int col = (b - 16) * 64 + col_in_blk;
        const float* __restrict__ p = w + (size_t)grp * (CH / 4) * D + col;
        float acc = 0.f;
        #pragma unroll 8
        for (int r = 0; r < CH / 4; ++r) acc += p[(size_t)r * D];
        red[grp][col_in_blk] = acc;
        __syncthreads();
        if (grp == 0)
            t[col] = (red[0][col_in_blk] + red[1][col_in_blk]) +
                     (red[2][col_in_blk] + red[3][col_in_blk]);
    }
}

// ---------------------------------------------------------------------------
// K3: one block per output row i. s_i = rowsum(w[i]), det_i = sum exp(s_i*c),
// out[i,j] = exp(s_i*t_j)/det_i.
// ---------------------------------------------------------------------------
__global__ __launch_bounds__(256) void out_kernel(
    const float* __restrict__ w, const float* __restrict__ c,
    const float* __restrict__ t, float* __restrict__ out) {
    const int i   = blockIdx.x;
    const int tid = threadIdx.x;
    __shared__ float red[256];

    float4 wv = reinterpret_cast<const float4*>(w + (size_t)i * D)[tid];
    red[tid] = (wv.x + wv.y) + (wv.z + wv.w);
    __syncthreads();
    for (int sft = 128; sft > 0; sft >>= 1) {
        if (tid < sft) red[tid] += red[tid + sft];
        __syncthreads();
    }
    const float s_i = red[0];
    __syncthreads();

    float4 cv = reinterpret_cast<const float4*>(c)[tid];
    red[tid] = (expf(s_i * cv.x) + expf(s_i * cv.y)) +
               (expf(s_i * cv.z) + expf(s_i * cv.w));
    __syncthreads();
    for (int sft = 128; sft > 0; sft >>= 1) {
        if (tid < sft) red[tid] += red[tid + sft];
        __syncthreads();
    }
    const float inv_det = 1.0f / red[0];

    float4 tv = reinterpret_cast<const float4*>(t)[tid];
    float4 o;
    o.x = expf(s_i * tv.x) * inv_det;
    o.y = expf(s_i * tv.y) * inv_det;
    o.z = expf(s_i * tv.z) * inv_det;
    o.w = expf(s_i * tv.w) * inv_det;
    reinterpret_cast<float4*>(out + (size_t)i * D)[tid] = o;
}

// ---------------------------------------------------------------------------
// launch
// ---------------------------------------------------------------------------
extern "C" void kernel_launch(void* const* d_in, const int* in_sizes, int n_in,
                              void* d_out, int out_size, void* d_ws, size_t ws_size,
                              hipStream_t stream) {
    const float* x = (const float*)d_in[0];
    const float* w = (const float*)d_in[1];
    float* out = (float*)d_out;

    char* ws = (char*)d_ws;
    float* c       = (float*)(ws);
    float* t       = (float*)(ws + 4096);
    float* partial = (float*)(ws + 8192);

    // nchunk: power of two, capped by workspace (ws is ~1 GiB in practice).
    size_t avail = (ws_size > 8192) ? (ws_size - 8192) : 0;
    int max_chunks = (int)(avail / (D * sizeof(float)));
    int nchunk = NCHUNK_DEFAULT;
    while (nchunk > 4 && nchunk > max_chunks) nchunk >>= 1;
    const int rows = N_ROWS / nchunk;

    colsum_partial_kernel<<<nchunk, 256, 0, stream>>>(x, partial, rows);
    reduce_ct_kernel<<<32, 256, 0, stream>>>(partial, nchunk, w, c, t);
    out_kernel<<<CH, 256, 0, stream>>>(w, c, t, out);
}

// Round 3
// 77.146 us; speedup vs baseline: 2.4890x; 1.0173x over previous
//
#include <hip/hip_runtime.h>

// Reference: x[65536][1024] f32, weight[128][1024] f32 -> out[128][1024] f32.
// out[i,j] = exp(s_i*t_j)/det_i; s=rowsum(w), t=colsum(w), c=colsum(x),
// det_i = sum_k exp(s_i*c_k).  Mandatory traffic: 256 MiB read of x.
constexpr int N_ROWS = 65536;
constexpr int D      = 1024;
constexpr int CH     = 128;
constexpr int NCHUNK = 2048;            // 8 blocks/CU -> 32 waves/CU (occupancy cap)
constexpr int ROWS   = N_ROWS / NCHUNK; // 32 rows per block

// ---------------------------------------------------------------------------
// K1: partial column sums. Block = contiguous 32-row slab; 256 thr x float4
// covers one 1024-col row per step. 4 independent accumulators; occupancy
// forced to 8 waves/SIMD via launch_bounds (VGPR <= 64) so the CU holds
// 32 waves x 4 KiB = 128 KiB of loads in flight.
// ---------------------------------------------------------------------------
__global__ __launch_bounds__(256, 8) void colsum_partial_kernel(
    const float* __restrict__ x, float* __restrict__ partial, int rows) {
    const int chunk = blockIdx.x;
    const int tid   = threadIdx.x;
    const float4* __restrict__ xr =
        reinterpret_cast<const float4*>(x) + (size_t)chunk * rows * (D / 4) + tid;

    float4 a0 = {0, 0, 0, 0}, a1 = {0, 0, 0, 0}, a2 = {0, 0, 0, 0}, a3 = {0, 0, 0, 0};
    for (int r = 0; r < rows; r += 4) {
        float4 v0 = xr[(size_t)(r + 0) * (D / 4)];
        float4 v1 = xr[(size_t)(r + 1) * (D / 4)];
        float4 v2 = xr[(size_t)(r + 2) * (D / 4)];
        float4 v3 = xr[(size_t)(r + 3) * (D / 4)];
        a0.x += v0.x; a0.y += v0.y; a0.z += v0.z; a0.w += v0.w;
        a1.x += v1.x; a1.y += v1.y; a1.z += v1.z; a1.w += v1.w;
        a2.x += v2.x; a2.y += v2.y; a2.z += v2.z; a2.w += v2.w;
        a3.x += v3.x; a3.y += v3.y; a3.z += v3.z; a3.w += v3.w;
    }
    float4 o;
    o.x = (a0.x + a1.x) + (a2.x + a3.x);
    o.y = (a0.y + a1.y) + (a2.y + a3.y);
    o.z = (a0.z + a1.z) + (a2.z + a3.z);
    o.w = (a0.w + a1.w) + (a2.w + a3.w);
    reinterpret_cast<float4*>(partial)[(size_t)chunk * (D / 4) + tid] = o;
}

// ---------------------------------------------------------------------------
// K2: blocks 0..31  : reduce partial[nchunk][1024] -> c[1024]
//     blocks 32..47 : column-sum weight             -> t[1024]
// c: block owns 32 cols; 256 thr = 8 chunk-groups x 32 cols; LDS combine.
// t: block owns 64 cols; 256 thr = 4 row-groups x 64 cols;  LDS combine.
// Fixed reduction order -> deterministic.
// ---------------------------------------------------------------------------
__global__ __launch_bounds__(256) void reduce_ct_kernel(
    const float* __restrict__ partial, int nchunk,
    const float* __restrict__ w,
    float* __restrict__ c, float* __restrict__ t) {
    const int b   = blockIdx.x;
    const int tid = threadIdx.x;
    __shared__ float red[256];

    if (b < 32) {
        const int col_in = tid & 31;
        const int grp    = tid >> 5;          // 0..7
        const int col    = b * 32 + col_in;
        const int cpg    = nchunk >> 3;       // chunks per group
        const float* __restrict__ p = partial + (size_t)grp * cpg * D + col;
        float acc = 0.f;
        #pragma unroll 8
        for (int ch = 0; ch < cpg; ++ch) acc += p[(size_t)ch * D];
        red[grp * 32 + col_in] = acc;
        __syncthreads();
        if (grp == 0) {
            float s = ((red[0 * 32 + col_in] + red[1 * 32 + col_in]) +
                       (red[2 * 32 + col_in] + red[3 * 32 + col_in])) +
                      ((red[4 * 32 + col_in] + red[5 * 32 + col_in]) +
                       (red[6 * 32 + col_in] + red[7 * 32 + col_in]));
            c[col] = s;
        }
    } else {
        const int col_in = tid & 63;
        const int grp    = tid >> 6;          // 0..3
        const int col    = (b - 32) * 64 + col_in;
        const float* __restrict__ p = w + (size_t)grp * (CH / 4) * D + col;
        float acc = 0.f;
        #pragma unroll 8
        for (int r = 0; r < CH / 4; ++r) acc += p[(size_t)r * D];
        red[grp * 64 + col_in] = acc;
        __syncthreads();
        if (grp == 0)
            t[col] = (red[0 * 64 + col_in] + red[1 * 64 + col_in]) +
                     (red[2 * 64 + col_in] + red[3 * 64 + col_in]);
    }
}

// ---------------------------------------------------------------------------
// K3: one block per output row i. s_i = rowsum(w[i]), det_i = sum exp(s_i*c),
// out[i,j] = exp(s_i*t_j)/det_i.
// ---------------------------------------------------------------------------
__global__ __launch_bounds__(256) void out_kernel(
    const float* __restrict__ w, const float* __restrict__ c,
    const float* __restrict__ t, float* __restrict__ out) {
    const int i   = blockIdx.x;
    const int tid = threadIdx.x;
    __shared__ float red[256];

    float4 wv = reinterpret_cast<const float4*>(w + (size_t)i * D)[tid];
    red[tid] = (wv.x + wv.y) + (wv.z + wv.w);
    __syncthreads();
    for (int sft = 128; sft > 0; sft >>= 1) {
        if (tid < sft) red[tid] += red[tid + sft];
        __syncthreads();
    }
    const float s_i = red[0];
    __syncthreads();

    float4 cv = reinterpret_cast<const float4*>(c)[tid];
    red[tid] = (expf(s_i * cv.x) + expf(s_i * cv.y)) +
               (expf(s_i * cv.z) + expf(s_i * cv.w));
    __syncthreads();
    for (int sft = 128; sft > 0; sft >>= 1) {
        if (tid < sft) red[tid] += red[tid + sft];
        __syncthreads();
    }
    const float inv_det = 1.0f / red[0];

    float4 tv = reinterpret_cast<const float4*>(t)[tid];
    float4 o;
    o.x = expf(s_i * tv.x) * inv_det;
    o.y = expf(s_i * tv.y) * inv_det;
    o.z = expf(s_i * tv.z) * inv_det;
    o.w = expf(s_i * tv.w) * inv_det;
    reinterpret_cast<float4*>(out + (size_t)i * D)[tid] = o;
}

// ---------------------------------------------------------------------------
// launch
// ---------------------------------------------------------------------------
extern "C" void kernel_launch(void* const* d_in, const int* in_sizes, int n_in,
                              void* d_out, int out_size, void* d_ws, size_t ws_size,
                              hipStream_t stream) {
    const float* x = (const float*)d_in[0];
    const float* w = (const float*)d_in[1];
    float* out = (float*)d_out;

    char* ws = (char*)d_ws;
    float* c       = (float*)(ws);
    float* t       = (float*)(ws + 4096);
    float* partial = (float*)(ws + 8192);

    // nchunk: power of two, capped by workspace (observed ws is ~1 GiB).
    size_t avail = (ws_size > 8192) ? (ws_size - 8192) : 0;
    int max_chunks = (int)(avail / (D * sizeof(float)));
    int nchunk = NCHUNK;
    while (nchunk > 8 && nchunk > max_chunks) nchunk >>= 1;
    const int rows = N_ROWS / nchunk;

    colsum_partial_kernel<<<nchunk, 256, 0, stream>>>(x, partial, rows);
    reduce_ct_kernel<<<48, 256, 0, stream>>>(partial, nchunk, w, c, t);
    out_kernel<<<CH, 256, 0, stream>>>(w, c, t, out);
}

// Round 5
// 70.554 us; speedup vs baseline: 2.7216x; 1.0934x over previous
//
#include <hip/hip_runtime.h>

// Reference: x[65536][1024] f32, weight[128][1024] f32 -> out[128][1024] f32.
// out[i,j] = exp(s_i*t_j)/det_i; s=rowsum(w), t=colsum(w), c=colsum(x),
// det_i = sum_k exp(s_i*c_k).  Mandatory traffic: 256 MiB read of x.
constexpr int N_ROWS = 65536;
constexpr int D      = 1024;
constexpr int CH     = 128;
constexpr int NCHUNK = 2048;

// clang-native vector type: __builtin_nontemporal_load accepts pointers to
// these (it rejects HIP_vector_type<float,4>*).
typedef float f32x4 __attribute__((ext_vector_type(4)));

// ---------------------------------------------------------------------------
// K1: partial column sums of x, moving-window order: block b reads rows
// {b, b+nchunk, b+2*nchunk, ...}. At any instant the machine reads 8 moving
// contiguous windows (8-deep unroll). Nontemporal: x is read-once, don't
// allocate it in L2/L3. 256 thr x 16B = one full 1024-col row per load.
// ---------------------------------------------------------------------------
__global__ __launch_bounds__(256, 4) void colsum_partial_kernel(
    const float* __restrict__ x, float* __restrict__ partial, int nchunk) {
    const int tid  = threadIdx.x;
    const int b    = blockIdx.x;
    const int iters = N_ROWS / nchunk;       // rows handled per block (32)
    const size_t rs   = D / 4;               // f32x4 per row
    const size_t step = (size_t)nchunk * rs; // one window step
    const f32x4* __restrict__ xr =
        reinterpret_cast<const f32x4*>(x) + (size_t)b * rs + tid;

    f32x4 a0 = 0.f, a1 = 0.f, a2 = 0.f, a3 = 0.f;
    f32x4 a4 = 0.f, a5 = 0.f, a6 = 0.f, a7 = 0.f;
    for (int j = 0; j < iters; j += 8) {
        const f32x4* p = xr + (size_t)j * step;
        f32x4 v0 = __builtin_nontemporal_load(p + 0 * step);
        f32x4 v1 = __builtin_nontemporal_load(p + 1 * step);
        f32x4 v2 = __builtin_nontemporal_load(p + 2 * step);
        f32x4 v3 = __builtin_nontemporal_load(p + 3 * step);
        f32x4 v4 = __builtin_nontemporal_load(p + 4 * step);
        f32x4 v5 = __builtin_nontemporal_load(p + 5 * step);
        f32x4 v6 = __builtin_nontemporal_load(p + 6 * step);
        f32x4 v7 = __builtin_nontemporal_load(p + 7 * step);
        a0 += v0; a1 += v1; a2 += v2; a3 += v3;
        a4 += v4; a5 += v5; a6 += v6; a7 += v7;
    }
    f32x4 o = ((a0 + a1) + (a2 + a3)) + ((a4 + a5) + (a6 + a7));
    reinterpret_cast<f32x4*>(partial)[(size_t)b * rs + tid] = o;
}

// ---------------------------------------------------------------------------
// K2: blocks 0..127  : reduce partial[nchunk][1024] -> c[1024]  (8 cols/block,
//                      32 chunk-groups x 8 cols per block, LDS tree combine)
//     blocks 128..255: column-sum weight -> t[1024] (8 cols, 32 grp x 4 rows)
// Fixed order -> deterministic.
// ---------------------------------------------------------------------------
__global__ __launch_bounds__(256) void reduce_ct_kernel(
    const float* __restrict__ partial, int nchunk,
    const float* __restrict__ w,
    float* __restrict__ c, float* __restrict__ t) {
    const int b     = blockIdx.x;
    const int tid   = threadIdx.x;
    const int colin = tid & 7;
    const int grp   = tid >> 3;   // 0..31
    __shared__ float red[32][8];

    float acc = 0.f;
    int col;
    if (b < 128) {
        col = b * 8 + colin;
        const int cpg = nchunk >> 5;   // chunks per group (64 @ nchunk=2048)
        const float* __restrict__ p = partial + (size_t)(grp * cpg) * D + col;
        #pragma unroll 8
        for (int ch = 0; ch < cpg; ++ch) acc += p[(size_t)ch * D];
    } else {
        col = (b - 128) * 8 + colin;
        const float* __restrict__ p = w + (size_t)(grp * (CH / 32)) * D + col;
        #pragma unroll
        for (int r = 0; r < CH / 32; ++r) acc += p[(size_t)r * D];
    }
    red[grp][colin] = acc;
    __syncthreads();
    for (int s = 16; s > 0; s >>= 1) {
        if (grp < s) red[grp][colin] += red[grp + s][colin];
        __syncthreads();
    }
    if (grp == 0) {
        if (b < 128) c[col] = red[0][colin];
        else         t[col] = red[0][colin];
    }
}

// ---------------------------------------------------------------------------
// K3: one block per output row i. Wave butterfly (__shfl_xor, 64-wide) +
// tiny LDS combine: 2 syncthreads total instead of 8.
// ---------------------------------------------------------------------------
__global__ __launch_bounds__(256) void out_kernel(
    const float* __restrict__ w, const float* __restrict__ c,
    const float* __restrict__ t, float* __restrict__ out) {
    const int i    = blockIdx.x;
    const int tid  = threadIdx.x;
    const int wid  = tid >> 6;
    const int lane = tid & 63;
    __shared__ float red[8];

    float4 wv = reinterpret_cast<const float4*>(w + (size_t)i * D)[tid];
    float sv = (wv.x + wv.y) + (wv.z + wv.w);
    #pragma unroll
    for (int m = 32; m > 0; m >>= 1) sv += __shfl_xor(sv, m, 64);
    if (lane == 0) red[wid] = sv;
    __syncthreads();
    const float s_i = (red[0] + red[1]) + (red[2] + red[3]);

    float4 cv = reinterpret_cast<const float4*>(c)[tid];
    float ev = (expf(s_i * cv.x) + expf(s_i * cv.y)) +
               (expf(s_i * cv.z) + expf(s_i * cv.w));
    #pragma unroll
    for (int m = 32; m > 0; m >>= 1) ev += __shfl_xor(ev, m, 64);
    if (lane == 0) red[4 + wid] = ev;
    __syncthreads();
    const float inv_det = 1.0f / ((red[4] + red[5]) + (red[6] + red[7]));

    float4 tv = reinterpret_cast<const float4*>(t)[tid];
    float4 o;
    o.x = expf(s_i * tv.x) * inv_det;
    o.y = expf(s_i * tv.y) * inv_det;
    o.z = expf(s_i * tv.z) * inv_det;
    o.w = expf(s_i * tv.w) * inv_det;
    reinterpret_cast<float4*>(out + (size_t)i * D)[tid] = o;
}

// ---------------------------------------------------------------------------
// launch
// ---------------------------------------------------------------------------
extern "C" void kernel_launch(void* const* d_in, const int* in_sizes, int n_in,
                              void* d_out, int out_size, void* d_ws, size_t ws_size,
                              hipStream_t stream) {
    const float* x = (const float*)d_in[0];
    const float* w = (const float*)d_in[1];
    float* out = (float*)d_out;

    char* ws = (char*)d_ws;
    float* c       = (float*)(ws);
    float* t       = (float*)(ws + 4096);
    float* partial = (float*)(ws + 8192);

    // nchunk: power of two >= 32 with iters % 8 == 0; ws is ~1 GiB in practice.
    int nchunk = NCHUNK;
    while (nchunk > 32 && (size_t)nchunk * D * sizeof(float) + 8192 > ws_size)
        nchunk >>= 1;

    colsum_partial_kernel<<<nchunk, 256, 0, stream>>>(x, partial, nchunk);
    reduce_ct_kernel<<<256, 256, 0, stream>>>(partial, nchunk, w, c, t);
    out_kernel<<<CH, 256, 0, stream>>>(w, c, t, out);
}